// Round 13
// baseline (95.140 us; speedup 1.0000x reference)
//
#include <hip/hip_runtime.h>
#include <hip/hip_bf16.h>
#include <cstdint>
#include <cstddef>

#define HEADS 16
#define HDIM  64
#define EMBED 1024
#define SEQ   2048
#define NB    2

typedef __attribute__((ext_vector_type(8))) short short8;
typedef __attribute__((ext_vector_type(4))) short s16x4;
typedef __attribute__((ext_vector_type(2))) float f32x2;
typedef __attribute__((ext_vector_type(4))) float f32x4;
typedef __attribute__((ext_vector_type(16))) float f32x16;

// fp32 -> bf16 (RNE) as raw short bits
__device__ __forceinline__ short f2bf(float f) {
    union { float f; uint32_t u; } in{f};
    uint32_t u = in.u;
    u += 0x7fffu + ((u >> 16) & 1u);
    return (short)(u >> 16);
}

// pack two fp32 -> one u32 of 2 bf16 (low = a, high = b)
__device__ __forceinline__ int cvtpk(float a, float b) {
    __hip_bfloat162 h = __float22bfloat162_rn(make_float2(a, b));
    int i;
    __builtin_memcpy(&i, &h, 4);
    return i;
}

// load 8 consecutive fp32 (32B aligned) and convert to bf16x8 (as short8)
__device__ __forceinline__ short8 load_cvt8(const float* __restrict__ p) {
    const f32x4* q = (const f32x4*)p;
    f32x4 v0 = q[0], v1 = q[1];
    short8 r;
    r[0] = f2bf(v0[0]); r[1] = f2bf(v0[1]); r[2] = f2bf(v0[2]); r[3] = f2bf(v0[3]);
    r[4] = f2bf(v1[0]); r[5] = f2bf(v1[1]); r[6] = f2bf(v1[2]); r[7] = f2bf(v1[3]);
    return r;
}

// ---------------- Kernel 0: small-weight pre-conversion to bf16 -------------
// Only Wq/Wk/Wv (3 blocks). Wq scaled by 0.125 * log2(e) (softmax 1/sqrt(64),
// exp2 domain). Wo conversion lives in attn_kernel's grid tail (it is only
// consumed by ogemm, which runs after attn).
__global__ __launch_bounds__(256) void wcvt_kernel(
    const float* __restrict__ Wq, const float* __restrict__ Wk,
    const float* __restrict__ Wv,
    short* __restrict__ Wqb, short* __restrict__ Wkb, short* __restrict__ Wvb) {
    int b = blockIdx.x, tid = threadIdx.x;
    const float* src = (b == 0) ? Wq : (b == 1) ? Wk : Wv;
    short* dst = (b == 0) ? Wqb : (b == 1) ? Wkb : Wvb;
    float scale = (b == 0) ? 0.125f * 1.44269504088896341f : 1.0f;
#pragma unroll
    for (int k = 0; k < 4; ++k) {
        int idx = tid * 16 + k * 4;
        f32x4 v = *(const f32x4*)(src + idx);
        s16x4 r;
        r[0] = f2bf(v[0] * scale); r[1] = f2bf(v[1] * scale);
        r[2] = f2bf(v[2] * scale); r[3] = f2bf(v[3] * scale);
        *(s16x4*)(dst + idx) = r;
    }
}

// ---------------- Kernel 1: unified Q/K/V projection ----------------
// grid (SEQ/64, HEADS, 6): z = op*2 + n, op 0=Q 1=K 2=V.
// Q: row-major Qp[nh][l][e].
// K/V: FRAGMENT-LINEAR layouts so attn reads are perfectly coalesced 1KB:
//   Kf[(nh*2+sp)*32 + t][dt][lane][j] = K[token=sp*1024+t*32+(lane&31)]
//                                        [d = dt*16 + (lane>>5)*8 + j]
//   Vf[(nh*2+sp)*32 + t][p ][lane][j] = V[token=sp*1024+t*32+(p>>1)*16+(lane>>5)*8+j]
//                                        [e = (p&1)*32 + (lane&31)]
__global__ __launch_bounds__(256) void proj_kernel(
    const float* __restrict__ qrys, const float* __restrict__ keys,
    const float* __restrict__ vals,
    const short* __restrict__ Wqb, const short* __restrict__ Wkb,
    const short* __restrict__ Wvb,
    short* __restrict__ Qp, short* __restrict__ Kf, short* __restrict__ Vf) {
    __shared__ short tile[64][72];
    int tid = threadIdx.x, lane = tid & 63, w = tid >> 6;
    int g = lane >> 4, c = lane & 15;
    int tt = blockIdx.x * 64;
    int h = blockIdx.y;
    int z = blockIdx.z;
    int op = z >> 1, n = z & 1;
    int nh = n * 16 + h;
    const float* src = (op == 0) ? qrys : (op == 1) ? keys : vals;
    const short* Wb = (op == 0) ? Wqb : (op == 1) ? Wkb : Wvb;

    int lt0 = tt + w * 16;
    const float* sp_ = src + ((size_t)(n * SEQ + lt0 + c) * 16 + h) * 64;
    short8 a0 = load_cvt8(sp_ + 8 * g);
    short8 a1 = load_cvt8(sp_ + 32 + 8 * g);
#pragma unroll
    for (int ot = 0; ot < 4; ++ot) {
        short8 b0 = *(const short8*)(Wb + (ot * 16 + c) * 64 + 8 * g);
        short8 b1 = *(const short8*)(Wb + (ot * 16 + c) * 64 + 32 + 8 * g);
        f32x4 acc = {0.f, 0.f, 0.f, 0.f};
        acc = __builtin_amdgcn_mfma_f32_16x16x32_bf16(a0, b0, acc, 0, 0, 0);
        acc = __builtin_amdgcn_mfma_f32_16x16x32_bf16(a1, b1, acc, 0, 0, 0);
        if (op == 2) {
#pragma unroll
            for (int r = 0; r < 4; ++r)
                tile[ot * 16 + c][w * 16 + 4 * g + r] = f2bf(acc[r]);  // [e][l]
        } else {
#pragma unroll
            for (int r = 0; r < 4; ++r)
                tile[w * 16 + 4 * g + r][ot * 16 + c] = f2bf(acc[r]);  // [l][e]
        }
    }
    __syncthreads();
    if (op == 0) {
#pragma unroll
        for (int it = 0; it < 2; ++it) {
            int idx = tid + it * 256;
            int row = idx >> 3, ch = idx & 7;
            short8 v = *(const short8*)(&tile[row][ch * 8]);
            *(short8*)(Qp + ((size_t)nh * SEQ + tt + row) * 64 + ch * 8) = v;
        }
    } else {
        short* dst = (op == 1) ? Kf : Vf;
        int spx = tt >> 10;                 // which K-split half
        int tbase = (tt >> 5) & 31;         // 32-token tile index within half
        size_t grp = (size_t)(nh * 2 + spx) * 32;
#pragma unroll
        for (int it = 0; it < 2; ++it) {
            int idx = tid + it * 256;
            int tl2 = idx >> 8;             // which of the 2 tiles in this block
            int p = (idx >> 6) & 3;         // page within tile
            int ln = idx & 63;
            int hi2 = ln >> 5, col2 = ln & 31;
            const short* srcp;
            if (op == 1) {
                // K: value = tile[token_local][d]
                srcp = &tile[tl2 * 32 + col2][p * 16 + hi2 * 8];
            } else {
                // V: value = tile[e][token_local]
                srcp = &tile[(p & 1) * 32 + col2][tl2 * 32 + (p >> 1) * 16 + hi2 * 8];
            }
            *(short8*)(dst + ((grp + tbase + tl2) * 4 + p) * 512 + ln * 8) =
                *(const short8*)srcp;
        }
    }
}

// ---------------- Kernel 3: flash attention (32x32 swapped-QK^T, split-K 2) --
// Best-measured configuration (r10/r12, 94.2-94.6us total): barrier-free,
// direct-global fragment-linear K/V (coalesced 1KB page loads),
// single-buffered, (256,4), no setprio, persistent-zero accumulator,
// packed l-accumulation. At its dataflow plateau (~51us across 7 structural
// variants, rounds 4-10). UNCHANGED. Grid tail (lid >= 1024) converts Wo.
__global__ __launch_bounds__(256, 4) void attn_kernel(
    const short* __restrict__ Qp, const short* __restrict__ Kf,
    const short* __restrict__ Vf, short* __restrict__ X,
    const float* __restrict__ Wo, short* __restrict__ Wob) {
    __shared__ float obuf[2][32][64];   // split-K combine: [qg][q][d]  16 KB
    __shared__ float larr[2][2][32];    // [qg][sp][q]                 512 B

    int tid = threadIdx.x, lane = tid & 63, wave = tid >> 6;
    int lid = blockIdx.x;

    // ---- grid tail: Wo fragment-linear conversion (ogemm B-operand) ----
    //   Wf[page = nb*32+kb][lane = g*16+c][j] = Wo[nb*16+c][kb*32+8g+j]
    if (lid >= 1024) {
        int o = (lid - 1024) * 1024 + tid * 4;   // short index (contiguous)
        int page = o >> 9, inp = o & 511;
        int nb = page >> 5, kb = page & 31;
        int lp = inp >> 3, jj = inp & 7;
        int row = nb * 16 + (lp & 15);
        int colf = kb * 32 + (lp >> 4) * 8 + jj;
        f32x4 v = *(const f32x4*)(Wo + row * 1024 + colf);
        s16x4 r;
        r[0] = f2bf(v[0]); r[1] = f2bf(v[1]); r[2] = f2bf(v[2]); r[3] = f2bf(v[3]);
        *(s16x4*)(Wob + o) = r;
        return;
    }

    int col = lane & 31, hi = lane >> 5;
    int qg = wave >> 1, sp = wave & 1;

    // XCD-aware remap: 4 nh per XCD, 32 q-blocks per nh
    int xcd = lid & 7, idx = lid >> 3;
    int nh = xcd * 4 + (idx & 3);
    int qb = idx >> 2;                   // 0..31
    int n = nh >> 4, h = nh & 15;
    int q0w = qb * 64 + qg * 32;

    const short* Qb = Qp + (size_t)nh * SEQ * 64;
    // fragment-linear bases: (nh,sp) group = 128 pages x 512 shorts = 1<<16
    const short* Kw = Kf + (((size_t)(nh * 2 + sp)) << 16) + lane * 8;
    const short* Vw = Vf + (((size_t)(nh * 2 + sp)) << 16) + lane * 8;

    // Q B-fragments (lane: q = q0w+col, d = 16t+8hi..+7)
    short8 qf[4];
#pragma unroll
    for (int t = 0; t < 4; ++t)
        qf[t] = *(const short8*)(Qb + (size_t)(q0w + col) * 64 + 16 * t + 8 * hi);

    f32x16 o0, o1, zac;
#pragma unroll
    for (int r = 0; r < 16; ++r) { o0[r] = 0.f; o1[r] = 0.f; zac[r] = 0.f; }
    f32x2 la2 = {0.f, 0.f};

#pragma unroll 1
    for (int t = 0; t < 32; ++t) {
        // single-buffered coalesced 1KB page loads for this tile
        short8 kf[4], vf[4];
#pragma unroll
        for (int dt = 0; dt < 4; ++dt)
            kf[dt] = *(const short8*)(Kw + ((size_t)(t * 4 + dt) << 9));
#pragma unroll
        for (int p = 0; p < 4; ++p)
            vf[p] = *(const short8*)(Vw + ((size_t)(t * 4 + p) << 9));

        // QK^T: S^T[k=32][q=32] over 4 d-chunks; C of first MFMA = zac
        f32x16 s = __builtin_amdgcn_mfma_f32_32x32x16_bf16(kf[0], qf[0], zac, 0, 0, 0);
#pragma unroll
        for (int dt = 1; dt < 4; ++dt)
            s = __builtin_amdgcn_mfma_f32_32x32x16_bf16(kf[dt], qf[dt], s, 0, 0, 0);

        // softmax (m = 0, exp2 domain; scale pre-folded into Wq)
#pragma unroll
        for (int r = 0; r < 16; r += 2) {
            s[r] = __builtin_amdgcn_exp2f(s[r]);
            s[r + 1] = __builtin_amdgcn_exp2f(s[r + 1]);
            la2 += (f32x2){s[r], s[r + 1]};
        }
        // pack P to bf16 pairs, permlane32_swap to build A-fragments
        int pk0 = cvtpk(s[0], s[1]),   pk1 = cvtpk(s[2], s[3]);
        int pk2 = cvtpk(s[4], s[5]),   pk3 = cvtpk(s[6], s[7]);
        int pk4 = cvtpk(s[8], s[9]),   pk5 = cvtpk(s[10], s[11]);
        int pk6 = cvtpk(s[12], s[13]), pk7 = cvtpk(s[14], s[15]);
        auto r02 = __builtin_amdgcn_permlane32_swap(pk0, pk2, false, false);
        auto r13 = __builtin_amdgcn_permlane32_swap(pk1, pk3, false, false);
        auto r46 = __builtin_amdgcn_permlane32_swap(pk4, pk6, false, false);
        auto r57 = __builtin_amdgcn_permlane32_swap(pk5, pk7, false, false);
        union { int i[4]; short8 s8; } pa0, pa1;
        pa0.i[0] = r02[0]; pa0.i[1] = r13[0]; pa0.i[2] = r02[1]; pa0.i[3] = r13[1];
        pa1.i[0] = r46[0]; pa1.i[1] = r57[0]; pa1.i[2] = r46[1]; pa1.i[3] = r57[1];
        // PV  (vf pages: 0=(kc0,nt0) 1=(kc0,nt1) 2=(kc1,nt0) 3=(kc1,nt1))
        o0 = __builtin_amdgcn_mfma_f32_32x32x16_bf16(pa0.s8, vf[0], o0, 0, 0, 0);
        o1 = __builtin_amdgcn_mfma_f32_32x32x16_bf16(pa0.s8, vf[1], o1, 0, 0, 0);
        o0 = __builtin_amdgcn_mfma_f32_32x32x16_bf16(pa1.s8, vf[2], o0, 0, 0, 0);
        o1 = __builtin_amdgcn_mfma_f32_32x32x16_bf16(pa1.s8, vf[3], o1, 0, 0, 0);
    }

    // fold the two half-lane partial l's (each lane then has l for q=col)
    float l_loc = la2[0] + la2[1];
    l_loc += __shfl_xor(l_loc, 32);

    // ---- split-K combine through LDS ----
    if (lane < 32) larr[qg][sp][col] = l_loc;
    if (sp == 0) {
#pragma unroll
        for (int r = 0; r < 16; ++r) {
            int rq = (r & 3) + 8 * (r >> 2) + 4 * hi;
            obuf[qg][rq][col] = o0[r];
            obuf[qg][rq][32 + col] = o1[r];
        }
    }
    __syncthreads();
    if (sp == 1) {
#pragma unroll
        for (int r = 0; r < 16; ++r) {
            int rq = (r & 3) + 8 * (r >> 2) + 4 * hi;
            float ltot = larr[qg][0][rq] + larr[qg][1][rq];
            float iv = 1.0f / ltot;
            float v0 = o0[r] + obuf[qg][rq][col];
            float v1 = o1[r] + obuf[qg][rq][32 + col];
            // fragment-linear X write (ogemm A-operand):
            //   v0 -> k = h*64 + col      (page (m>>4)*32 + h*2)
            //   v1 -> k = h*64 + 32 + col (page +1), same in-page offset
            int m = n * SEQ + q0w + rq;
            size_t base = (((size_t)(m >> 4) * 32 + h * 2) << 9) +
                          (size_t)(m & 15) * 8 + ((col >> 3) << 7) + (col & 7);
            X[base] = f2bf(v0 * iv);
            X[base + 512] = f2bf(v1 * iv);
        }
    }
}

// ---------------- Kernel 4: output GEMM: out = X @ Wo^T + bo ----------------
// A (X) and B (Wo) are both fragment-linear: every load is a fully-coalesced
// 1KB page (base + lane*16B); consecutive K-steps are contiguous addresses.
// 128x64 tiles (r10 best; 64x64 regressed in r11 — worse arithmetic
// intensity). THIS ROUND: prefetch distance 1 -> 2. Grid gives only
// 2 blocks/CU = 2 waves/SIMD (TLP fixed by grid, not registers), so each
// K-step exposed most of the ~300-400cyc L2 latency behind a single
// 8-MFMA phase (~40cyc). Unroll K by 2 with FOUR buffer sets; issue both
// next-pair loads (s+2, s+3) before computing the current pair -> load-to-
// use distance = 2 MFMA phases (~100-160cyc/wave, x2 waves). Extra ~48
// VGPR is free: occupancy is grid-limited, no min-waves bound -> no spill.
__global__ __launch_bounds__(256) void ogemm_kernel(
    const short* __restrict__ Xf, const short* __restrict__ Wf,
    const float* __restrict__ bo, float* __restrict__ out) {
    int tid = threadIdx.x, lane = tid & 63, wave = tid >> 6;
    int g = lane >> 4, c = lane & 15;
    int wr = wave >> 1, wc = wave & 1;
    int m0 = blockIdx.x * 128 + wr * 64;
    int n0 = blockIdx.y * 64 + wc * 32;

    f32x4 acc[4][2];
#pragma unroll
    for (int i = 0; i < 4; ++i)
#pragma unroll
        for (int j = 0; j < 2; ++j) acc[i][j] = (f32x4){0.f, 0.f, 0.f, 0.f};

    // page bases: A pages (mb*32 + s), B pages (nb*32 + s); 512 shorts/page
    const short* Xp = Xf + (((size_t)(blockIdx.x * 8 + wr * 4) * 32) << 9) + lane * 8;
    const short* Wp = Wf + (((size_t)(blockIdx.y * 4 + wc * 2) * 32) << 9) + lane * 8;

#define LDA(buf, s)                                                            \
    {                                                                          \
        _Pragma("unroll")                                                      \
        for (int i = 0; i < 4; ++i)                                            \
            buf[i] = *(const short8*)(Xp + (((size_t)i * 32 + (s)) << 9));     \
    }
#define LDB(buf, s)                                                            \
    {                                                                          \
        _Pragma("unroll")                                                      \
        for (int j = 0; j < 2; ++j)                                            \
            buf[j] = *(const short8*)(Wp + (((size_t)j * 32 + (s)) << 9));     \
    }
#define MM(abuf, bbuf)                                                         \
    {                                                                          \
        _Pragma("unroll")                                                      \
        for (int i = 0; i < 4; ++i)                                            \
            _Pragma("unroll")                                                  \
            for (int j = 0; j < 2; ++j)                                        \
                acc[i][j] = __builtin_amdgcn_mfma_f32_16x16x32_bf16(           \
                    abuf[i], bbuf[j], acc[i][j], 0, 0, 0);                     \
    }

    short8 aE[4], bE[2], aO[4], bO[2];   // even/odd current pair
    short8 aE2[4], bE2[2], aO2[4], bO2[2];  // incoming pair
    LDA(aE, 0); LDB(bE, 0);
    LDA(aO, 1); LDB(bO, 1);

#pragma unroll 1
    for (int s = 0; s < 32; s += 4) {
        // ---- steps s, s+1 current in E/O; prefetch s+2, s+3 into E2/O2 ----
        LDA(aE2, s + 2); LDB(bE2, s + 2);
        LDA(aO2, s + 3); LDB(bO2, s + 3);
        MM(aE, bE);
        MM(aO, bO);
        // ---- steps s+2, s+3 current in E2/O2; prefetch s+4, s+5 ----
        if (s + 4 < 32) {
            LDA(aE, s + 4); LDB(bE, s + 4);
            LDA(aO, s + 5); LDB(bO, s + 5);
        }
        MM(aE2, bE2);
        MM(aO2, bO2);
    }
#undef LDA
#undef LDB
#undef MM

    float bias[2] = {bo[n0 + c], bo[n0 + 16 + c]};
#pragma unroll
    for (int i = 0; i < 4; ++i)
#pragma unroll
        for (int j = 0; j < 2; ++j)
#pragma unroll
            for (int r = 0; r < 4; ++r)
                out[(size_t)(m0 + i * 16 + 4 * g + r) * EMBED + n0 + j * 16 + c] =
                    acc[i][j][r] + bias[j];
}

extern "C" void kernel_launch(void* const* d_in, const int* in_sizes, int n_in,
                              void* d_out, int out_size, void* d_ws, size_t ws_size,
                              hipStream_t stream) {
    const float* vals = (const float*)d_in[0];
    const float* keys = (const float*)d_in[1];
    const float* qrys = (const float*)d_in[2];
    const float* Wv = (const float*)d_in[3];
    const float* Wk = (const float*)d_in[4];
    const float* Wq = (const float*)d_in[5];
    const float* Wo = (const float*)d_in[6];
    const float* bo = (const float*)d_in[7];
    float* out = (float*)d_out;

    char* ws = (char*)d_ws;
    const size_t sz_bf = (size_t)NB * HEADS * SEQ * HDIM * sizeof(short);  // 8 MB
    short* Qp = (short*)(ws);
    short* Kf = (short*)(ws + sz_bf);
    short* Vf = (short*)(ws + 2 * sz_bf);
    short* X = (short*)(ws + 3 * sz_bf);                       // 8 MB bf16 (fragment-linear)
    short* Wob = (short*)(ws + 4 * sz_bf);                     // 2 MB (fragment-linear)
    short* Wqb = (short*)(ws + 4 * sz_bf + 2 * 1024 * 1024);   // 8 KB each
    short* Wkb = Wqb + 64 * 64;
    short* Wvb = Wkb + 64 * 64;

    wcvt_kernel<<<dim3(3), dim3(256), 0, stream>>>(Wq, Wk, Wv, Wqb, Wkb, Wvb);
    proj_kernel<<<dim3(SEQ / 64, HEADS, 6), dim3(256), 0, stream>>>(
        qrys, keys, vals, Wqb, Wkb, Wvb, Qp, Kf, Vf);
    attn_kernel<<<dim3(2048), dim3(256), 0, stream>>>(Qp, Kf, Vf, X, Wo, Wob);
    ogemm_kernel<<<dim3(NB * SEQ / 128, EMBED / 64), dim3(256), 0, stream>>>(X, Wob, bo, out);
}

// Round 14
// 93.995 us; speedup vs baseline: 1.0122x; 1.0122x over previous
//
#include <hip/hip_runtime.h>
#include <hip/hip_bf16.h>
#include <cstdint>
#include <cstddef>

#define HEADS 16
#define HDIM  64
#define EMBED 1024
#define SEQ   2048
#define NB    2

typedef __attribute__((ext_vector_type(8))) short short8;
typedef __attribute__((ext_vector_type(4))) short s16x4;
typedef __attribute__((ext_vector_type(2))) float f32x2;
typedef __attribute__((ext_vector_type(4))) float f32x4;
typedef __attribute__((ext_vector_type(16))) float f32x16;

// fp32 -> bf16 (RNE) as raw short bits
__device__ __forceinline__ short f2bf(float f) {
    union { float f; uint32_t u; } in{f};
    uint32_t u = in.u;
    u += 0x7fffu + ((u >> 16) & 1u);
    return (short)(u >> 16);
}

// pack two fp32 -> one u32 of 2 bf16 (low = a, high = b)
__device__ __forceinline__ int cvtpk(float a, float b) {
    __hip_bfloat162 h = __float22bfloat162_rn(make_float2(a, b));
    int i;
    __builtin_memcpy(&i, &h, 4);
    return i;
}

// load 8 consecutive fp32 (32B aligned) and convert to bf16x8 (as short8)
__device__ __forceinline__ short8 load_cvt8(const float* __restrict__ p) {
    const f32x4* q = (const f32x4*)p;
    f32x4 v0 = q[0], v1 = q[1];
    short8 r;
    r[0] = f2bf(v0[0]); r[1] = f2bf(v0[1]); r[2] = f2bf(v0[2]); r[3] = f2bf(v0[3]);
    r[4] = f2bf(v1[0]); r[5] = f2bf(v1[1]); r[6] = f2bf(v1[2]); r[7] = f2bf(v1[3]);
    return r;
}

// ---------------- Kernel 0: small-weight pre-conversion to bf16 -------------
// Only Wq/Wk/Wv (3 blocks). Wq scaled by 0.125 * log2(e) (softmax 1/sqrt(64),
// exp2 domain). Wo conversion lives in attn_kernel's grid tail (it is only
// consumed by ogemm, which runs after attn).
__global__ __launch_bounds__(256) void wcvt_kernel(
    const float* __restrict__ Wq, const float* __restrict__ Wk,
    const float* __restrict__ Wv,
    short* __restrict__ Wqb, short* __restrict__ Wkb, short* __restrict__ Wvb) {
    int b = blockIdx.x, tid = threadIdx.x;
    const float* src = (b == 0) ? Wq : (b == 1) ? Wk : Wv;
    short* dst = (b == 0) ? Wqb : (b == 1) ? Wkb : Wvb;
    float scale = (b == 0) ? 0.125f * 1.44269504088896341f : 1.0f;
#pragma unroll
    for (int k = 0; k < 4; ++k) {
        int idx = tid * 16 + k * 4;
        f32x4 v = *(const f32x4*)(src + idx);
        s16x4 r;
        r[0] = f2bf(v[0] * scale); r[1] = f2bf(v[1] * scale);
        r[2] = f2bf(v[2] * scale); r[3] = f2bf(v[3] * scale);
        *(s16x4*)(dst + idx) = r;
    }
}

// ---------------- Kernel 1: unified Q/K/V projection ----------------
// grid (SEQ/64, HEADS, 6): z = op*2 + n, op 0=Q 1=K 2=V.
// Q: row-major Qp[nh][l][e].
// K/V: FRAGMENT-LINEAR layouts so attn reads are perfectly coalesced 1KB:
//   Kf[(nh*2+sp)*32 + t][dt][lane][j] = K[token=sp*1024+t*32+(lane&31)]
//                                        [d = dt*16 + (lane>>5)*8 + j]
//   Vf[(nh*2+sp)*32 + t][p ][lane][j] = V[token=sp*1024+t*32+(p>>1)*16+(lane>>5)*8+j]
//                                        [e = (p&1)*32 + (lane&31)]
__global__ __launch_bounds__(256) void proj_kernel(
    const float* __restrict__ qrys, const float* __restrict__ keys,
    const float* __restrict__ vals,
    const short* __restrict__ Wqb, const short* __restrict__ Wkb,
    const short* __restrict__ Wvb,
    short* __restrict__ Qp, short* __restrict__ Kf, short* __restrict__ Vf) {
    __shared__ short tile[64][72];
    int tid = threadIdx.x, lane = tid & 63, w = tid >> 6;
    int g = lane >> 4, c = lane & 15;
    int tt = blockIdx.x * 64;
    int h = blockIdx.y;
    int z = blockIdx.z;
    int op = z >> 1, n = z & 1;
    int nh = n * 16 + h;
    const float* src = (op == 0) ? qrys : (op == 1) ? keys : vals;
    const short* Wb = (op == 0) ? Wqb : (op == 1) ? Wkb : Wvb;

    int lt0 = tt + w * 16;
    const float* sp_ = src + ((size_t)(n * SEQ + lt0 + c) * 16 + h) * 64;
    short8 a0 = load_cvt8(sp_ + 8 * g);
    short8 a1 = load_cvt8(sp_ + 32 + 8 * g);
#pragma unroll
    for (int ot = 0; ot < 4; ++ot) {
        short8 b0 = *(const short8*)(Wb + (ot * 16 + c) * 64 + 8 * g);
        short8 b1 = *(const short8*)(Wb + (ot * 16 + c) * 64 + 32 + 8 * g);
        f32x4 acc = {0.f, 0.f, 0.f, 0.f};
        acc = __builtin_amdgcn_mfma_f32_16x16x32_bf16(a0, b0, acc, 0, 0, 0);
        acc = __builtin_amdgcn_mfma_f32_16x16x32_bf16(a1, b1, acc, 0, 0, 0);
        if (op == 2) {
#pragma unroll
            for (int r = 0; r < 4; ++r)
                tile[ot * 16 + c][w * 16 + 4 * g + r] = f2bf(acc[r]);  // [e][l]
        } else {
#pragma unroll
            for (int r = 0; r < 4; ++r)
                tile[w * 16 + 4 * g + r][ot * 16 + c] = f2bf(acc[r]);  // [l][e]
        }
    }
    __syncthreads();
    if (op == 0) {
#pragma unroll
        for (int it = 0; it < 2; ++it) {
            int idx = tid + it * 256;
            int row = idx >> 3, ch = idx & 7;
            short8 v = *(const short8*)(&tile[row][ch * 8]);
            *(short8*)(Qp + ((size_t)nh * SEQ + tt + row) * 64 + ch * 8) = v;
        }
    } else {
        short* dst = (op == 1) ? Kf : Vf;
        int spx = tt >> 10;                 // which K-split half
        int tbase = (tt >> 5) & 31;         // 32-token tile index within half
        size_t grp = (size_t)(nh * 2 + spx) * 32;
#pragma unroll
        for (int it = 0; it < 2; ++it) {
            int idx = tid + it * 256;
            int tl2 = idx >> 8;             // which of the 2 tiles in this block
            int p = (idx >> 6) & 3;         // page within tile
            int ln = idx & 63;
            int hi2 = ln >> 5, col2 = ln & 31;
            const short* srcp;
            if (op == 1) {
                // K: value = tile[token_local][d]
                srcp = &tile[tl2 * 32 + col2][p * 16 + hi2 * 8];
            } else {
                // V: value = tile[e][token_local]
                srcp = &tile[(p & 1) * 32 + col2][tl2 * 32 + (p >> 1) * 16 + hi2 * 8];
            }
            *(short8*)(dst + ((grp + tbase + tl2) * 4 + p) * 512 + ln * 8) =
                *(const short8*)srcp;
        }
    }
}

// ---------------- Kernel 3: flash attention (32x32 swapped-QK^T, split-K 2) --
// Best-measured configuration (r10/r12, 94.2-94.6us total): barrier-free,
// direct-global fragment-linear K/V (coalesced 1KB page loads),
// single-buffered, (256,4), no setprio, persistent-zero accumulator,
// packed l-accumulation. At its dataflow plateau (~51us across 8 structural
// variants, rounds 4-13). Grid tail (lid >= 1024) converts Wo -> Wob.
__global__ __launch_bounds__(256, 4) void attn_kernel(
    const short* __restrict__ Qp, const short* __restrict__ Kf,
    const short* __restrict__ Vf, short* __restrict__ X,
    const float* __restrict__ Wo, short* __restrict__ Wob) {
    __shared__ float obuf[2][32][64];   // split-K combine: [qg][q][d]  16 KB
    __shared__ float larr[2][2][32];    // [qg][sp][q]                 512 B

    int tid = threadIdx.x, lane = tid & 63, wave = tid >> 6;
    int lid = blockIdx.x;

    // ---- grid tail: Wo fragment-linear conversion (ogemm B-operand) ----
    //   Wf[page = nb*32+kb][lane = g*16+c][j] = Wo[nb*16+c][kb*32+8g+j]
    if (lid >= 1024) {
        int o = (lid - 1024) * 1024 + tid * 4;   // short index (contiguous)
        int page = o >> 9, inp = o & 511;
        int nb = page >> 5, kb = page & 31;
        int lp = inp >> 3, jj = inp & 7;
        int row = nb * 16 + (lp & 15);
        int colf = kb * 32 + (lp >> 4) * 8 + jj;
        f32x4 v = *(const f32x4*)(Wo + row * 1024 + colf);
        s16x4 r;
        r[0] = f2bf(v[0]); r[1] = f2bf(v[1]); r[2] = f2bf(v[2]); r[3] = f2bf(v[3]);
        *(s16x4*)(Wob + o) = r;
        return;
    }

    int col = lane & 31, hi = lane >> 5;
    int qg = wave >> 1, sp = wave & 1;

    // XCD-aware remap: 4 nh per XCD, 32 q-blocks per nh
    int xcd = lid & 7, idx = lid >> 3;
    int nh = xcd * 4 + (idx & 3);
    int qb = idx >> 2;                   // 0..31
    int n = nh >> 4, h = nh & 15;
    int q0w = qb * 64 + qg * 32;

    const short* Qb = Qp + (size_t)nh * SEQ * 64;
    // fragment-linear bases: (nh,sp) group = 128 pages x 512 shorts = 1<<16
    const short* Kw = Kf + (((size_t)(nh * 2 + sp)) << 16) + lane * 8;
    const short* Vw = Vf + (((size_t)(nh * 2 + sp)) << 16) + lane * 8;

    // Q B-fragments (lane: q = q0w+col, d = 16t+8hi..+7)
    short8 qf[4];
#pragma unroll
    for (int t = 0; t < 4; ++t)
        qf[t] = *(const short8*)(Qb + (size_t)(q0w + col) * 64 + 16 * t + 8 * hi);

    f32x16 o0, o1, zac;
#pragma unroll
    for (int r = 0; r < 16; ++r) { o0[r] = 0.f; o1[r] = 0.f; zac[r] = 0.f; }
    f32x2 la2 = {0.f, 0.f};

#pragma unroll 1
    for (int t = 0; t < 32; ++t) {
        // single-buffered coalesced 1KB page loads for this tile
        short8 kf[4], vf[4];
#pragma unroll
        for (int dt = 0; dt < 4; ++dt)
            kf[dt] = *(const short8*)(Kw + ((size_t)(t * 4 + dt) << 9));
#pragma unroll
        for (int p = 0; p < 4; ++p)
            vf[p] = *(const short8*)(Vw + ((size_t)(t * 4 + p) << 9));

        // QK^T: S^T[k=32][q=32] over 4 d-chunks; C of first MFMA = zac
        f32x16 s = __builtin_amdgcn_mfma_f32_32x32x16_bf16(kf[0], qf[0], zac, 0, 0, 0);
#pragma unroll
        for (int dt = 1; dt < 4; ++dt)
            s = __builtin_amdgcn_mfma_f32_32x32x16_bf16(kf[dt], qf[dt], s, 0, 0, 0);

        // softmax (m = 0, exp2 domain; scale pre-folded into Wq)
#pragma unroll
        for (int r = 0; r < 16; r += 2) {
            s[r] = __builtin_amdgcn_exp2f(s[r]);
            s[r + 1] = __builtin_amdgcn_exp2f(s[r + 1]);
            la2 += (f32x2){s[r], s[r + 1]};
        }
        // pack P to bf16 pairs, permlane32_swap to build A-fragments
        int pk0 = cvtpk(s[0], s[1]),   pk1 = cvtpk(s[2], s[3]);
        int pk2 = cvtpk(s[4], s[5]),   pk3 = cvtpk(s[6], s[7]);
        int pk4 = cvtpk(s[8], s[9]),   pk5 = cvtpk(s[10], s[11]);
        int pk6 = cvtpk(s[12], s[13]), pk7 = cvtpk(s[14], s[15]);
        auto r02 = __builtin_amdgcn_permlane32_swap(pk0, pk2, false, false);
        auto r13 = __builtin_amdgcn_permlane32_swap(pk1, pk3, false, false);
        auto r46 = __builtin_amdgcn_permlane32_swap(pk4, pk6, false, false);
        auto r57 = __builtin_amdgcn_permlane32_swap(pk5, pk7, false, false);
        union { int i[4]; short8 s8; } pa0, pa1;
        pa0.i[0] = r02[0]; pa0.i[1] = r13[0]; pa0.i[2] = r02[1]; pa0.i[3] = r13[1];
        pa1.i[0] = r46[0]; pa1.i[1] = r57[0]; pa1.i[2] = r46[1]; pa1.i[3] = r57[1];
        // PV  (vf pages: 0=(kc0,nt0) 1=(kc0,nt1) 2=(kc1,nt0) 3=(kc1,nt1))
        o0 = __builtin_amdgcn_mfma_f32_32x32x16_bf16(pa0.s8, vf[0], o0, 0, 0, 0);
        o1 = __builtin_amdgcn_mfma_f32_32x32x16_bf16(pa0.s8, vf[1], o1, 0, 0, 0);
        o0 = __builtin_amdgcn_mfma_f32_32x32x16_bf16(pa1.s8, vf[2], o0, 0, 0, 0);
        o1 = __builtin_amdgcn_mfma_f32_32x32x16_bf16(pa1.s8, vf[3], o1, 0, 0, 0);
    }

    // fold the two half-lane partial l's (each lane then has l for q=col)
    float l_loc = la2[0] + la2[1];
    l_loc += __shfl_xor(l_loc, 32);

    // ---- split-K combine through LDS ----
    if (lane < 32) larr[qg][sp][col] = l_loc;
    if (sp == 0) {
#pragma unroll
        for (int r = 0; r < 16; ++r) {
            int rq = (r & 3) + 8 * (r >> 2) + 4 * hi;
            obuf[qg][rq][col] = o0[r];
            obuf[qg][rq][32 + col] = o1[r];
        }
    }
    __syncthreads();
    if (sp == 1) {
#pragma unroll
        for (int r = 0; r < 16; ++r) {
            int rq = (r & 3) + 8 * (r >> 2) + 4 * hi;
            float ltot = larr[qg][0][rq] + larr[qg][1][rq];
            float iv = 1.0f / ltot;
            float v0 = o0[r] + obuf[qg][rq][col];
            float v1 = o1[r] + obuf[qg][rq][32 + col];
            // fragment-linear X write (ogemm A-operand):
            //   v0 -> k = h*64 + col      (page (m>>4)*32 + h*2)
            //   v1 -> k = h*64 + 32 + col (page +1), same in-page offset
            int m = n * SEQ + q0w + rq;
            size_t base = (((size_t)(m >> 4) * 32 + h * 2) << 9) +
                          (size_t)(m & 15) * 8 + ((col >> 3) << 7) + (col & 7);
            X[base] = f2bf(v0 * iv);
            X[base + 512] = f2bf(v1 * iv);
        }
    }
}

// ---------------- Kernel 4: output GEMM: out = X @ Wo^T + bo ----------------
// A (X) and B (Wo) are both fragment-linear: every load is a fully-coalesced
// 1KB page (base + lane*16B); consecutive K-steps are contiguous addresses.
// 128x64 tiles, distance-1 prefetch (r10/r12 best; 64x64 tiles regressed in
// r11, distance-2 prefetch neutral-negative in r13).
__global__ __launch_bounds__(256) void ogemm_kernel(
    const short* __restrict__ Xf, const short* __restrict__ Wf,
    const float* __restrict__ bo, float* __restrict__ out) {
    int tid = threadIdx.x, lane = tid & 63, wave = tid >> 6;
    int g = lane >> 4, c = lane & 15;
    int wr = wave >> 1, wc = wave & 1;
    int m0 = blockIdx.x * 128 + wr * 64;
    int n0 = blockIdx.y * 64 + wc * 32;

    f32x4 acc[4][2];
#pragma unroll
    for (int i = 0; i < 4; ++i)
#pragma unroll
        for (int j = 0; j < 2; ++j) acc[i][j] = (f32x4){0.f, 0.f, 0.f, 0.f};

    // page bases: A pages (mb*32 + s), B pages (nb*32 + s); 512 shorts/page
    const short* Xp = Xf + (((size_t)(blockIdx.x * 8 + wr * 4) * 32) << 9) + lane * 8;
    const short* Wp = Wf + (((size_t)(blockIdx.y * 4 + wc * 2) * 32) << 9) + lane * 8;

    short8 a[4], b[2];
#pragma unroll
    for (int i = 0; i < 4; ++i) a[i] = *(const short8*)(Xp + ((size_t)i * 32 << 9));
#pragma unroll
    for (int j = 0; j < 2; ++j) b[j] = *(const short8*)(Wp + ((size_t)j * 32 << 9));

    for (int s = 1; s <= 32; ++s) {
        short8 an[4], bn[2];
        if (s < 32) {
#pragma unroll
            for (int i = 0; i < 4; ++i)
                an[i] = *(const short8*)(Xp + (((size_t)i * 32 + s) << 9));
#pragma unroll
            for (int j = 0; j < 2; ++j)
                bn[j] = *(const short8*)(Wp + (((size_t)j * 32 + s) << 9));
        }
#pragma unroll
        for (int i = 0; i < 4; ++i)
#pragma unroll
            for (int j = 0; j < 2; ++j)
                acc[i][j] = __builtin_amdgcn_mfma_f32_16x16x32_bf16(a[i], b[j], acc[i][j], 0, 0, 0);
        if (s < 32) {
#pragma unroll
            for (int i = 0; i < 4; ++i) a[i] = an[i];
#pragma unroll
            for (int j = 0; j < 2; ++j) b[j] = bn[j];
        }
    }

    float bias[2] = {bo[n0 + c], bo[n0 + 16 + c]};
#pragma unroll
    for (int i = 0; i < 4; ++i)
#pragma unroll
        for (int j = 0; j < 2; ++j)
#pragma unroll
            for (int r = 0; r < 4; ++r)
                out[(size_t)(m0 + i * 16 + 4 * g + r) * EMBED + n0 + j * 16 + c] =
                    acc[i][j][r] + bias[j];
}

extern "C" void kernel_launch(void* const* d_in, const int* in_sizes, int n_in,
                              void* d_out, int out_size, void* d_ws, size_t ws_size,
                              hipStream_t stream) {
    const float* vals = (const float*)d_in[0];
    const float* keys = (const float*)d_in[1];
    const float* qrys = (const float*)d_in[2];
    const float* Wv = (const float*)d_in[3];
    const float* Wk = (const float*)d_in[4];
    const float* Wq = (const float*)d_in[5];
    const float* Wo = (const float*)d_in[6];
    const float* bo = (const float*)d_in[7];
    float* out = (float*)d_out;

    char* ws = (char*)d_ws;
    const size_t sz_bf = (size_t)NB * HEADS * SEQ * HDIM * sizeof(short);  // 8 MB
    short* Qp = (short*)(ws);
    short* Kf = (short*)(ws + sz_bf);
    short* Vf = (short*)(ws + 2 * sz_bf);
    short* X = (short*)(ws + 3 * sz_bf);                       // 8 MB bf16 (fragment-linear)
    short* Wob = (short*)(ws + 4 * sz_bf);                     // 2 MB (fragment-linear)
    short* Wqb = (short*)(ws + 4 * sz_bf + 2 * 1024 * 1024);   // 8 KB each
    short* Wkb = Wqb + 64 * 64;
    short* Wvb = Wkb + 64 * 64;

    wcvt_kernel<<<dim3(3), dim3(256), 0, stream>>>(Wq, Wk, Wv, Wqb, Wkb, Wvb);
    proj_kernel<<<dim3(SEQ / 64, HEADS, 6), dim3(256), 0, stream>>>(
        qrys, keys, vals, Wqb, Wkb, Wvb, Qp, Kf, Vf);
    attn_kernel<<<dim3(2048), dim3(256), 0, stream>>>(Qp, Kf, Vf, X, Wo, Wob);
    ogemm_kernel<<<dim3(NB * SEQ / 128, EMBED / 64), dim3(256), 0, stream>>>(X, Wob, bo, out);
}